// Round 1
// baseline (275.504 us; speedup 1.0000x reference)
//
#include <hip/hip_runtime.h>

// RecformerPooler: grouped nanmean over (attr, item) pairs.
// Shapes: hidden [64,1024,768] f32, ids [64,1024] i32, out [64,3,32,768] f32.
// Strategy: one block per (batch, attr, item) output segment (6144 blocks).
//   Phase 1: scan this batch's ids (int4-vectorized), collect matching token
//            indices into LDS (order-independent via LDS atomic counter).
//   Phase 2: gather-sum the matching hidden rows with coalesced float4 loads
//            (192 of 256 threads cover H=768), divide by count (0/0 -> NaN).
// Every valid hidden row is read exactly once across the grid; invalid rows
// are never read. No global atomics; LDS use is 4.2 KB -> 8 blocks/CU.

#define ATTR_N 3
#define ITEM_N 32
#define SEGS (ATTR_N * ITEM_N)   // 96
#define B_DIM 64
#define L_DIM 1024
#define H_DIM 768

__global__ __launch_bounds__(256, 4) void recformer_pool_kernel(
    const float* __restrict__ hidden,
    const int*   __restrict__ attr,
    const int*   __restrict__ item,
    float*       __restrict__ out)
{
    __shared__ int match_idx[L_DIM];
    __shared__ int match_cnt;

    const int blk = blockIdx.x;           // [0, 64*96)
    const int b   = blk / SEGS;
    const int seg = blk % SEGS;
    const int ta  = seg / ITEM_N + 1;     // target attr id (1..3)
    const int ti  = seg % ITEM_N + 1;     // target item id (1..32)
    const int tid = threadIdx.x;

    if (tid == 0) match_cnt = 0;
    __syncthreads();

    // ---- Phase 1: scan ids, collect matching token indices ----
    {
        const int4* attr4 = (const int4*)(attr + b * L_DIM);
        const int4* item4 = (const int4*)(item + b * L_DIM);
        const int4 av = attr4[tid];       // 256 threads * 4 tokens = 1024
        const int4 iv = item4[tid];
        const int l0 = tid * 4;
        if (av.x == ta && iv.x == ti) { int p = atomicAdd(&match_cnt, 1); match_idx[p] = l0;     }
        if (av.y == ta && iv.y == ti) { int p = atomicAdd(&match_cnt, 1); match_idx[p] = l0 + 1; }
        if (av.z == ta && iv.z == ti) { int p = atomicAdd(&match_cnt, 1); match_idx[p] = l0 + 2; }
        if (av.w == ta && iv.w == ti) { int p = atomicAdd(&match_cnt, 1); match_idx[p] = l0 + 3; }
    }
    __syncthreads();
    const int cnt = match_cnt;

    // ---- Phase 2: gather-sum matching rows, coalesced float4 ----
    if (tid < (H_DIM / 4)) {              // 192 threads x float4 = 768 floats
        const float* base = hidden + (size_t)b * L_DIM * H_DIM + tid * 4;
        float4 acc = make_float4(0.f, 0.f, 0.f, 0.f);

        int k = 0;
        for (; k + 1 < cnt; k += 2) {     // 2-way unroll: two loads in flight
            const float4 v0 = *(const float4*)(base + (size_t)match_idx[k]     * H_DIM);
            const float4 v1 = *(const float4*)(base + (size_t)match_idx[k + 1] * H_DIM);
            acc.x += v0.x; acc.y += v0.y; acc.z += v0.z; acc.w += v0.w;
            acc.x += v1.x; acc.y += v1.y; acc.z += v1.z; acc.w += v1.w;
        }
        if (k < cnt) {
            const float4 v = *(const float4*)(base + (size_t)match_idx[k] * H_DIM);
            acc.x += v.x; acc.y += v.y; acc.z += v.z; acc.w += v.w;
        }

        const float c = (float)cnt;       // cnt==0 -> 0/0 -> NaN (== nanmean)
        float4 r;
        r.x = acc.x / c; r.y = acc.y / c; r.z = acc.z / c; r.w = acc.w / c;
        *(float4*)(out + (size_t)blk * H_DIM + tid * 4) = r;
    }
}

extern "C" void kernel_launch(void* const* d_in, const int* in_sizes, int n_in,
                              void* d_out, int out_size, void* d_ws, size_t ws_size,
                              hipStream_t stream) {
    // setup_inputs order: [0] attention_mask (unused), [1] hidden_states,
    //                     [2] attr_type_ids, [3] item_position_ids
    const float* hidden = (const float*)d_in[1];
    const int*   attr   = (const int*)d_in[2];
    const int*   item   = (const int*)d_in[3];
    float*       out    = (float*)d_out;

    recformer_pool_kernel<<<dim3(B_DIM * SEGS), dim3(256), 0, stream>>>(
        hidden, attr, item, out);
}